// Round 5
// baseline (416.284 us; speedup 1.0000x reference)
//
#include <hip/hip_runtime.h>
#include <hip/hip_bf16.h>

typedef __attribute__((ext_vector_type(8))) short bf16x8;
typedef __attribute__((ext_vector_type(4))) float f32x4;

#define SEQ 2048
#define NB 4
#define NH 16
#define HID 1024

__device__ __forceinline__ short f2bf(float f) {
  __hip_bfloat16 h = __float2bfloat16(f);
  union { __hip_bfloat16 h; short s; } u; u.h = h; return u.s;
}

__device__ __forceinline__ void gload_lds16(const void* g, void* l) {
  __builtin_amdgcn_global_load_lds((const __attribute__((address_space(1))) void*)g,
                                   (__attribute__((address_space(3))) void*)l, 16, 0, 0);
}

__global__ void cvt_f32_bf16(const float4* __restrict__ in, short4* __restrict__ out, int n4) {
  int i = blockIdx.x * 256 + threadIdx.x;
  if (i >= n4) return;
  float4 v = in[i];
  short4 o;
  o.x = f2bf(v.x); o.y = f2bf(v.y); o.z = f2bf(v.z); o.w = f2bf(v.w);
  out[i] = o;
}

// C = A @ B^T (+bias). A: [M,1024] bf16 row-major. B: [N,1024] bf16 row-major.
// MODE 0: fused QKV. Q,K -> bf16 [B,H,S,64] (Q scaled 0.125). V -> bf16 [B,H,64,S] (transposed).
// MODE 1: O-proj, writes fp32 [M,1024] + bias.
template<int MODE>
__global__ __launch_bounds__(256, 2)
void gemm_bf16(const short* __restrict__ A,
               const short* __restrict__ B0, const short* __restrict__ B1, const short* __restrict__ B2,
               const float* __restrict__ bias0, const float* __restrict__ bias1, const float* __restrict__ bias2,
               short* __restrict__ o0, short* __restrict__ o1, short* __restrict__ o2,
               float* __restrict__ of) {
  __shared__ __align__(16) short As[128*64];
  __shared__ __align__(16) short Bs[128*64];
  const int tid = threadIdx.x;
  const int wave = tid >> 6, lane = tid & 63;
  const int lr = lane & 15, lk = lane >> 4;
  const int m0 = blockIdx.y * 128;
  const int n0 = blockIdx.x * 128;

  const short* Bm; const float* bias; int nloc; int proj = 0;
  if (MODE == 0) {
    proj = n0 >> 10;
    Bm   = proj == 0 ? B0 : (proj == 1 ? B1 : B2);
    bias = proj == 0 ? bias0 : (proj == 1 ? bias1 : bias2);
    nloc = n0 & 1023;
  } else { Bm = B0; bias = bias0; nloc = n0; }

  f32x4 acc[4][4];
  #pragma unroll
  for (int m = 0; m < 4; ++m)
    #pragma unroll
    for (int n = 0; n < 4; ++n) acc[m][n] = (f32x4){0.f,0.f,0.f,0.f};

  const int wr = (wave >> 1) * 64, wc = (wave & 1) * 64;

  for (int kt = 0; kt < 1024; kt += 64) {
    #pragma unroll
    for (int is = 0; is < 4; ++is) {
      int slot = is*256 + tid;
      int r = slot >> 3;
      int cs = (slot & 7) ^ (r & 7);
      gload_lds16(A  + (m0  + r)*1024 + kt + cs*8, As + (is*256 + wave*64)*8);
      gload_lds16(Bm + (nloc+ r)*1024 + kt + cs*8, Bs + (is*256 + wave*64)*8);
    }
    __syncthreads();
    #pragma unroll
    for (int kk = 0; kk < 2; ++kk) {
      bf16x8 av[4], bv[4];
      #pragma unroll
      for (int m = 0; m < 4; ++m) {
        int r = wr + m*16 + lr;
        av[m] = *(const bf16x8*)(As + (r*8 + ((kk*4 + lk) ^ (r & 7)))*8);
      }
      #pragma unroll
      for (int n = 0; n < 4; ++n) {
        int r = wc + n*16 + lr;
        bv[n] = *(const bf16x8*)(Bs + (r*8 + ((kk*4 + lk) ^ (r & 7)))*8);
      }
      #pragma unroll
      for (int m = 0; m < 4; ++m)
        #pragma unroll
        for (int n = 0; n < 4; ++n)
          acc[m][n] = __builtin_amdgcn_mfma_f32_16x16x32_bf16(av[m], bv[n], acc[m][n], 0, 0, 0);
    }
    __syncthreads();
  }

  // Epilogue. C/D frag: col = lane&15, row = (lane>>4)*4 + j  [m89].
  if (MODE == 0) {
    if (proj < 2) {
      short* outp = proj == 0 ? o0 : o1;
      const float scale = (proj == 0) ? 0.125f : 1.0f;
      #pragma unroll
      for (int n = 0; n < 4; ++n) {
        int col = nloc + wc + n*16 + lr;
        int h = col >> 6, d = col & 63;
        float bvv = bias[col];
        #pragma unroll
        for (int m = 0; m < 4; ++m)
          #pragma unroll
          for (int j = 0; j < 4; ++j) {
            int row = m0 + wr + m*16 + lk*4 + j;
            int b = row >> 11, s = row & 2047;
            outp[(((b*NH + h)*SEQ + s) << 6) + d] = f2bf((acc[m][n][j] + bvv) * scale);
          }
      }
    } else {
      // V -> transposed [B,H,64,S]; j contiguous in s -> packed 8B stores
      #pragma unroll
      for (int n = 0; n < 4; ++n) {
        int col = nloc + wc + n*16 + lr;
        int h = col >> 6, d = col & 63;
        float bvv = bias[col];
        #pragma unroll
        for (int m = 0; m < 4; ++m) {
          int row = m0 + wr + m*16 + lk*4;
          int b = row >> 11, s = row & 2047;
          short4 vv;
          vv.x = f2bf(acc[m][n][0] + bvv);
          vv.y = f2bf(acc[m][n][1] + bvv);
          vv.z = f2bf(acc[m][n][2] + bvv);
          vv.w = f2bf(acc[m][n][3] + bvv);
          *(short4*)(o2 + (((b*NH + h)*64 + d)*SEQ + s)) = vv;
        }
      }
    }
  } else {
    #pragma unroll
    for (int n = 0; n < 4; ++n) {
      int col = n0 + wc + n*16 + lr;
      float bvv = bias[col];
      #pragma unroll
      for (int m = 0; m < 4; ++m)
        #pragma unroll
        for (int j = 0; j < 4; ++j) {
          int row = m0 + wr + m*16 + lk*4 + j;
          of[row*HID + col] = acc[m][n][j] + bvv;
        }
    }
  }
}

// Flash attention, double-buffered K/V, 1 barrier/tile, defer-max.
// Q,K: [B,H,S,64] bf16 (Q pre-scaled 0.125). VT: [B,H,64,S] bf16. O: [B,S,H*64] bf16.
__global__ __launch_bounds__(256, 4)
void attn_fwd(const short* __restrict__ Q, const short* __restrict__ K,
              const short* __restrict__ VT, const float* __restrict__ head_mask,
              short* __restrict__ O) {
  __shared__ __align__(16) short Ks[2][64*64];   // [kv][d], swizzled f=r&7
  __shared__ __align__(16) short Vs[2][64*64];   // [d][kv], swizzled f=r&7
  __shared__ __align__(16) short Ps[4][16*64];   // per-wave P [q][kv], swizzled f=row>>1
  const int tid = threadIdx.x;
  const int wave = tid >> 6, lane = tid & 63;
  const int lr = lane & 15, lk = lane >> 4;
  const int bh = blockIdx.y;
  const int h = bh & (NH - 1);
  const int q0 = blockIdx.x * 64;
  const short* Qh = Q  + bh * SEQ * 64;
  const short* Kh = K  + bh * SEQ * 64;
  const short* Vh = VT + bh * 64 * SEQ;

  auto STAGE = [&](int buf, int kv0) {
    #pragma unroll
    for (int is = 0; is < 2; ++is) {
      int slot = is*256 + tid;
      int r = slot >> 3;
      int cs = (slot & 7) ^ (r & 7);
      gload_lds16(Kh + (kv0 + r)*64 + cs*8, Ks[buf] + (is*256 + wave*64)*8);
      gload_lds16(Vh + r*SEQ + kv0 + cs*8, Vs[buf] + (is*256 + wave*64)*8);
    }
  };

  // Q A-fragments: row = lane&15, k = (lane>>4)*8 + j
  bf16x8 qf[2];
  {
    const short* qr = Qh + (q0 + wave*16 + lr)*64 + lk*8;
    qf[0] = *(const bf16x8*)qr;
    qf[1] = *(const bf16x8*)(qr + 32);
  }

  float row_m[4], row_l[4];
  f32x4 oacc[4];
  #pragma unroll
  for (int j = 0; j < 4; ++j) { row_m[j] = -1e30f; row_l[j] = 0.f; }
  #pragma unroll
  for (int n = 0; n < 4; ++n) oacc[n] = (f32x4){0.f,0.f,0.f,0.f};

  STAGE(0, 0);
  __syncthreads();   // drain prologue stage

  const int NT = SEQ / 64;
  for (int t = 0; t < NT; ++t) {
    const int cur = t & 1;
    if (t + 1 < NT) STAGE(cur ^ 1, (t + 1) * 64);   // prefetch under compute

    // S = Q @ K^T : frag n covers kv cols [n*16, +16)
    f32x4 sc[4];
    #pragma unroll
    for (int n = 0; n < 4; ++n) sc[n] = (f32x4){0.f,0.f,0.f,0.f};
    #pragma unroll
    for (int kk = 0; kk < 2; ++kk)
      #pragma unroll
      for (int n = 0; n < 4; ++n) {
        int r = n*16 + lr;
        bf16x8 bv = *(const bf16x8*)(Ks[cur] + (r*8 + ((kk*4 + lk) ^ (r & 7)))*8);
        sc[n] = __builtin_amdgcn_mfma_f32_16x16x32_bf16(qf[kk], bv, sc[n], 0, 0, 0);
      }

    // Online softmax. q-row = lk*4+j, lanes [lk*16, +16), reg j.
    float pmax[4];
    #pragma unroll
    for (int j = 0; j < 4; ++j) {
      float v = fmaxf(fmaxf(sc[0][j], sc[1][j]), fmaxf(sc[2][j], sc[3][j]));
      v = fmaxf(v, __shfl_xor(v, 1));
      v = fmaxf(v, __shfl_xor(v, 2));
      v = fmaxf(v, __shfl_xor(v, 4));
      v = fmaxf(v, __shfl_xor(v, 8));
      pmax[j] = v;
    }
    // defer-max (T13): only rescale when some row's max grew past THR=8
    bool ok = (pmax[0] <= row_m[0] + 8.f) && (pmax[1] <= row_m[1] + 8.f) &&
              (pmax[2] <= row_m[2] + 8.f) && (pmax[3] <= row_m[3] + 8.f);
    if (!__all(ok)) {
      #pragma unroll
      for (int j = 0; j < 4; ++j) {
        float mn = fmaxf(row_m[j], pmax[j]);
        float ps = __expf(row_m[j] - mn);
        row_m[j] = mn;
        row_l[j] *= ps;
        #pragma unroll
        for (int n = 0; n < 4; ++n) oacc[n][j] *= ps;
      }
    }
    float rs[4] = {0.f, 0.f, 0.f, 0.f};
    #pragma unroll
    for (int n = 0; n < 4; ++n)
      #pragma unroll
      for (int j = 0; j < 4; ++j) {
        float p = __expf(sc[n][j] - row_m[j]);
        sc[n][j] = p;
        rs[j] += p;
      }
    #pragma unroll
    for (int j = 0; j < 4; ++j) {
      float v = rs[j];
      v += __shfl_xor(v, 1);
      v += __shfl_xor(v, 2);
      v += __shfl_xor(v, 4);
      v += __shfl_xor(v, 8);
      row_l[j] += v;
    }

    // P -> per-wave LDS (same-wave write->read: no barrier, lgkmcnt suffices)
    short* Pw = Ps[wave];
    #pragma unroll
    for (int n = 0; n < 4; ++n)
      #pragma unroll
      for (int j = 0; j < 4; ++j) {
        int row = lk*4 + j;
        int col = n*16 + lr;
        int byteoff = row*128 + (((col >> 3) ^ (row >> 1))*16) + (col & 7)*2;
        *(short*)((char*)Pw + byteoff) = f2bf(sc[n][j]);
      }

    // O += P @ V ; frag n covers d cols [n*16, +16)
    #pragma unroll
    for (int kk = 0; kk < 2; ++kk) {
      bf16x8 av = *(const bf16x8*)(Pw + (lr*8 + ((kk*4 + lk) ^ (lr >> 1)))*8);
      #pragma unroll
      for (int n = 0; n < 4; ++n) {
        int r = n*16 + lr;
        bf16x8 bv = *(const bf16x8*)(Vs[cur] + (r*8 + ((kk*4 + lk) ^ (r & 7)))*8);
        oacc[n] = __builtin_amdgcn_mfma_f32_16x16x32_bf16(av, bv, oacc[n], 0, 0, 0);
      }
    }
    // Single barrier/tile: all waves done reading buf[cur] before restage at t+1;
    // syncthreads' vmcnt(0) drain also retires this tile's prefetch.
    __syncthreads();
  }

  const float hm = head_mask[h];
  const int b = bh >> 4;
  #pragma unroll
  for (int j = 0; j < 4; ++j) {
    int q = q0 + wave*16 + lk*4 + j;
    float inv = hm / row_l[j];
    int rowbase = (b*SEQ + q)*HID + h*64;
    #pragma unroll
    for (int n = 0; n < 4; ++n)
      O[rowbase + n*16 + lr] = f2bf(oacc[n][j] * inv);
  }
}

extern "C" void kernel_launch(void* const* d_in, const int* in_sizes, int n_in,
                              void* d_out, int out_size, void* d_ws, size_t ws_size,
                              hipStream_t stream) {
  const float* x  = (const float*)d_in[0];
  const float* Wq = (const float*)d_in[1];
  const float* bq = (const float*)d_in[2];
  const float* Wk = (const float*)d_in[3];
  const float* bk = (const float*)d_in[4];
  const float* Wv = (const float*)d_in[5];
  const float* bv = (const float*)d_in[6];
  const float* Wo = (const float*)d_in[7];
  const float* bo = (const float*)d_in[8];
  const float* hm = (const float*)d_in[9];
  float* out = (float*)d_out;
  char* ws = (char*)d_ws;

  short* xb  = (short*)(ws);
  short* wqb = (short*)(ws + 16777216);
  short* wkb = (short*)(ws + 18874368);
  short* wvb = (short*)(ws + 20971520);
  short* wob = (short*)(ws + 23068672);
  short* Qb  = (short*)(ws + 25165824);
  short* Kb  = (short*)(ws + 41943040);
  short* Vb  = (short*)(ws + 58720256);   // V^T [B,H,64,S]
  short* AOb = (short*)(ws + 75497472);

  cvt_f32_bf16<<<8192, 256, 0, stream>>>((const float4*)x,  (short4*)xb,  2097152);
  cvt_f32_bf16<<<1024, 256, 0, stream>>>((const float4*)Wq, (short4*)wqb, 262144);
  cvt_f32_bf16<<<1024, 256, 0, stream>>>((const float4*)Wk, (short4*)wkb, 262144);
  cvt_f32_bf16<<<1024, 256, 0, stream>>>((const float4*)Wv, (short4*)wvb, 262144);
  cvt_f32_bf16<<<1024, 256, 0, stream>>>((const float4*)Wo, (short4*)wob, 262144);

  gemm_bf16<0><<<dim3(24, 64), 256, 0, stream>>>(xb, wqb, wkb, wvb, bq, bk, bv,
                                                 Qb, Kb, Vb, nullptr);
  attn_fwd<<<dim3(32, 64), 256, 0, stream>>>(Qb, Kb, Vb, hm, AOb);
  gemm_bf16<1><<<dim3(8, 64), 256, 0, stream>>>(AOb, wob, nullptr, nullptr, bo, nullptr, nullptr,
                                                nullptr, nullptr, nullptr, out);
}

// Round 6
// 390.940 us; speedup vs baseline: 1.0648x; 1.0648x over previous
//
#include <hip/hip_runtime.h>
#include <hip/hip_bf16.h>

typedef __attribute__((ext_vector_type(8))) short bf16x8;
typedef __attribute__((ext_vector_type(4))) float f32x4;

#define SEQ 2048
#define NB 4
#define NH 16
#define HID 1024
#define QBLK 128

template<int N> struct IC { static constexpr int v = N; };

__device__ __forceinline__ short f2bf(float f) {
  __hip_bfloat16 h = __float2bfloat16(f);
  union { __hip_bfloat16 h; short s; } u; u.h = h; return u.s;
}

__device__ __forceinline__ void gload_lds16(const void* g, void* l) {
  __builtin_amdgcn_global_load_lds((const __attribute__((address_space(1))) void*)g,
                                   (__attribute__((address_space(3))) void*)l, 16, 0, 0);
}

__global__ void cvt_f32_bf16(const float4* __restrict__ in, short4* __restrict__ out, int n4) {
  int i = blockIdx.x * 256 + threadIdx.x;
  if (i >= n4) return;
  float4 v = in[i];
  short4 o;
  o.x = f2bf(v.x); o.y = f2bf(v.y); o.z = f2bf(v.z); o.w = f2bf(v.w);
  out[i] = o;
}

// C = A @ B^T (+bias). MODE 0: fused QKV -> Q,K [B,H,S,64] (Q*0.125), V^T [B,H,64,S].
// MODE 1: O-proj -> fp32 [M,1024] + bias.
template<int MODE>
__global__ __launch_bounds__(256, 2)
void gemm_bf16(const short* __restrict__ A,
               const short* __restrict__ B0, const short* __restrict__ B1, const short* __restrict__ B2,
               const float* __restrict__ bias0, const float* __restrict__ bias1, const float* __restrict__ bias2,
               short* __restrict__ o0, short* __restrict__ o1, short* __restrict__ o2,
               float* __restrict__ of) {
  __shared__ __align__(16) short As[128*64];
  __shared__ __align__(16) short Bs[128*64];
  const int tid = threadIdx.x;
  const int wave = tid >> 6, lane = tid & 63;
  const int lr = lane & 15, lk = lane >> 4;
  const int m0 = blockIdx.y * 128;
  const int n0 = blockIdx.x * 128;

  const short* Bm; const float* bias; int nloc; int proj = 0;
  if (MODE == 0) {
    proj = n0 >> 10;
    Bm   = proj == 0 ? B0 : (proj == 1 ? B1 : B2);
    bias = proj == 0 ? bias0 : (proj == 1 ? bias1 : bias2);
    nloc = n0 & 1023;
  } else { Bm = B0; bias = bias0; nloc = n0; }

  f32x4 acc[4][4];
  #pragma unroll
  for (int m = 0; m < 4; ++m)
    #pragma unroll
    for (int n = 0; n < 4; ++n) acc[m][n] = (f32x4){0.f,0.f,0.f,0.f};

  const int wr = (wave >> 1) * 64, wc = (wave & 1) * 64;

  for (int kt = 0; kt < 1024; kt += 64) {
    #pragma unroll
    for (int is = 0; is < 4; ++is) {
      int slot = is*256 + tid;
      int r = slot >> 3;
      int cs = (slot & 7) ^ (r & 7);
      gload_lds16(A  + (m0  + r)*1024 + kt + cs*8, As + (is*256 + wave*64)*8);
      gload_lds16(Bm + (nloc+ r)*1024 + kt + cs*8, Bs + (is*256 + wave*64)*8);
    }
    __syncthreads();
    #pragma unroll
    for (int kk = 0; kk < 2; ++kk) {
      bf16x8 av[4], bv[4];
      #pragma unroll
      for (int m = 0; m < 4; ++m) {
        int r = wr + m*16 + lr;
        av[m] = *(const bf16x8*)(As + (r*8 + ((kk*4 + lk) ^ (r & 7)))*8);
      }
      #pragma unroll
      for (int n = 0; n < 4; ++n) {
        int r = wc + n*16 + lr;
        bv[n] = *(const bf16x8*)(Bs + (r*8 + ((kk*4 + lk) ^ (r & 7)))*8);
      }
      #pragma unroll
      for (int m = 0; m < 4; ++m)
        #pragma unroll
        for (int n = 0; n < 4; ++n)
          acc[m][n] = __builtin_amdgcn_mfma_f32_16x16x32_bf16(av[m], bv[n], acc[m][n], 0, 0, 0);
    }
    __syncthreads();
  }

  if (MODE == 0) {
    if (proj < 2) {
      short* outp = proj == 0 ? o0 : o1;
      const float scale = (proj == 0) ? 0.125f : 1.0f;
      #pragma unroll
      for (int n = 0; n < 4; ++n) {
        int col = nloc + wc + n*16 + lr;
        int h = col >> 6, d = col & 63;
        float bvv = bias[col];
        #pragma unroll
        for (int m = 0; m < 4; ++m)
          #pragma unroll
          for (int j = 0; j < 4; ++j) {
            int row = m0 + wr + m*16 + lk*4 + j;
            int b = row >> 11, s = row & 2047;
            outp[(((b*NH + h)*SEQ + s) << 6) + d] = f2bf((acc[m][n][j] + bvv) * scale);
          }
      }
    } else {
      #pragma unroll
      for (int n = 0; n < 4; ++n) {
        int col = nloc + wc + n*16 + lr;
        int h = col >> 6, d = col & 63;
        float bvv = bias[col];
        #pragma unroll
        for (int m = 0; m < 4; ++m) {
          int row = m0 + wr + m*16 + lk*4;
          int b = row >> 11, s = row & 2047;
          short4 vv;
          vv.x = f2bf(acc[m][n][0] + bvv);
          vv.y = f2bf(acc[m][n][1] + bvv);
          vv.z = f2bf(acc[m][n][2] + bvv);
          vv.w = f2bf(acc[m][n][3] + bvv);
          *(short4*)(o2 + (((b*NH + h)*64 + d)*SEQ + s)) = vv;
        }
      }
    }
  } else {
    #pragma unroll
    for (int n = 0; n < 4; ++n) {
      int col = n0 + wc + n*16 + lr;
      float bvv = bias[col];
      #pragma unroll
      for (int m = 0; m < 4; ++m)
        #pragma unroll
        for (int j = 0; j < 4; ++j) {
          int row = m0 + wr + m*16 + lk*4 + j;
          of[row*HID + col] = acc[m][n][j] + bvv;
        }
    }
  }
}

// Flash attention. QBLK=128: wave owns 32 q-rows = 2 independent 16-row groups
// (2x ILP on the softmax/MFMA chain). Double-buffered K/V with COMPILE-TIME buffer
// index (template CUR) so the prefetch provably doesn't alias current-tile reads.
// Q,K: [B,H,S,64] bf16 (Q*0.125). VT: [B,H,64,S]. O: [B,S,H*64] bf16.
__global__ __launch_bounds__(256, 3)
void attn_fwd(const short* __restrict__ Q, const short* __restrict__ K,
              const short* __restrict__ VT, const float* __restrict__ head_mask,
              short* __restrict__ O) {
  __shared__ __align__(16) short Ks[2][64*64];      // [kv][d], swizzled f=r&7
  __shared__ __align__(16) short Vs[2][64*64];      // [d][kv], swizzled f=r&7
  __shared__ __align__(16) short Ps[4][2][16*64];   // per-wave, per-group P, f=row>>1
  const int tid = threadIdx.x;
  const int wave = tid >> 6, lane = tid & 63;
  const int lr = lane & 15, lk = lane >> 4;
  const int bh = blockIdx.y;
  const int h = bh & (NH - 1);
  const int q0 = blockIdx.x * QBLK;
  const short* Qh = Q  + bh * SEQ * 64;
  const short* Kh = K  + bh * SEQ * 64;
  const short* Vh = VT + bh * 64 * SEQ;

  auto STAGE = [&](int buf, int kv0) {
    #pragma unroll
    for (int is = 0; is < 2; ++is) {
      int slot = is*256 + tid;
      int r = slot >> 3;
      int cs = (slot & 7) ^ (r & 7);
      gload_lds16(Kh + (kv0 + r)*64 + cs*8, Ks[buf] + (is*256 + wave*64)*8);
      gload_lds16(Vh + r*SEQ + kv0 + cs*8, Vs[buf] + (is*256 + wave*64)*8);
    }
  };

  // Q A-fragments for both 16-row groups: row = lane&15, k = (lane>>4)*8 + j
  bf16x8 qf[2][2];
  #pragma unroll
  for (int mg = 0; mg < 2; ++mg) {
    const short* qr = Qh + (q0 + wave*32 + mg*16 + lr)*64 + lk*8;
    qf[mg][0] = *(const bf16x8*)qr;
    qf[mg][1] = *(const bf16x8*)(qr + 32);
  }

  float row_m[2][4], row_l[2][4];
  f32x4 oacc[2][4];
  #pragma unroll
  for (int mg = 0; mg < 2; ++mg) {
    #pragma unroll
    for (int j = 0; j < 4; ++j) { row_m[mg][j] = -1e30f; row_l[mg][j] = 0.f; }
    #pragma unroll
    for (int n = 0; n < 4; ++n) oacc[mg][n] = (f32x4){0.f,0.f,0.f,0.f};
  }

  STAGE(0, 0);
  __syncthreads();

  const int NT = SEQ / 64;

  auto tile = [&](auto curc, int t) {
    constexpr int CUR = decltype(curc)::v;   // compile-time buffer index
    if (t + 1 < NT) STAGE(CUR ^ 1, (t + 1) * 64);   // true overlapped prefetch

    // S = Q @ K^T for both groups; B-frag shared
    f32x4 sc[2][4];
    #pragma unroll
    for (int mg = 0; mg < 2; ++mg)
      #pragma unroll
      for (int n = 0; n < 4; ++n) sc[mg][n] = (f32x4){0.f,0.f,0.f,0.f};
    #pragma unroll
    for (int kk = 0; kk < 2; ++kk)
      #pragma unroll
      for (int n = 0; n < 4; ++n) {
        int r = n*16 + lr;
        bf16x8 bv = *(const bf16x8*)(Ks[CUR] + (r*8 + ((kk*4 + lk) ^ (r & 7)))*8);
        sc[0][n] = __builtin_amdgcn_mfma_f32_16x16x32_bf16(qf[0][kk], bv, sc[0][n], 0, 0, 0);
        sc[1][n] = __builtin_amdgcn_mfma_f32_16x16x32_bf16(qf[1][kk], bv, sc[1][n], 0, 0, 0);
      }

    // Online softmax, two independent chains (q-row = lk*4+j within group)
    float pmax[2][4];
    #pragma unroll
    for (int mg = 0; mg < 2; ++mg)
      #pragma unroll
      for (int j = 0; j < 4; ++j) {
        float v = fmaxf(fmaxf(sc[mg][0][j], sc[mg][1][j]), fmaxf(sc[mg][2][j], sc[mg][3][j]));
        v = fmaxf(v, __shfl_xor(v, 1));
        v = fmaxf(v, __shfl_xor(v, 2));
        v = fmaxf(v, __shfl_xor(v, 4));
        v = fmaxf(v, __shfl_xor(v, 8));
        pmax[mg][j] = v;
      }
    bool ok = true;
    #pragma unroll
    for (int mg = 0; mg < 2; ++mg)
      #pragma unroll
      for (int j = 0; j < 4; ++j) ok = ok && (pmax[mg][j] <= row_m[mg][j] + 8.f);
    if (!__all(ok)) {   // defer-max (T13): rescale only when max grew past THR=8
      #pragma unroll
      for (int mg = 0; mg < 2; ++mg)
        #pragma unroll
        for (int j = 0; j < 4; ++j) {
          float mn = fmaxf(row_m[mg][j], pmax[mg][j]);
          float ps = __expf(row_m[mg][j] - mn);
          row_m[mg][j] = mn;
          row_l[mg][j] *= ps;
          #pragma unroll
          for (int n = 0; n < 4; ++n) oacc[mg][n][j] *= ps;
        }
    }
    #pragma unroll
    for (int mg = 0; mg < 2; ++mg) {
      float rs[4] = {0.f, 0.f, 0.f, 0.f};
      #pragma unroll
      for (int n = 0; n < 4; ++n)
        #pragma unroll
        for (int j = 0; j < 4; ++j) {
          float p = __expf(sc[mg][n][j] - row_m[mg][j]);
          sc[mg][n][j] = p;
          rs[j] += p;
        }
      #pragma unroll
      for (int j = 0; j < 4; ++j) {
        float v = rs[j];
        v += __shfl_xor(v, 1);
        v += __shfl_xor(v, 2);
        v += __shfl_xor(v, 4);
        v += __shfl_xor(v, 8);
        row_l[mg][j] += v;
      }
    }

    // P -> per-wave per-group LDS (same-wave write->read, no barrier needed)
    #pragma unroll
    for (int mg = 0; mg < 2; ++mg) {
      short* Pw = Ps[wave][mg];
      #pragma unroll
      for (int n = 0; n < 4; ++n)
        #pragma unroll
        for (int j = 0; j < 4; ++j) {
          int row = lk*4 + j;
          int col = n*16 + lr;
          int byteoff = row*128 + (((col >> 3) ^ (row >> 1))*16) + (col & 7)*2;
          *(short*)((char*)Pw + byteoff) = f2bf(sc[mg][n][j]);
        }
    }

    // O += P @ V for both groups; V B-frag shared
    #pragma unroll
    for (int kk = 0; kk < 2; ++kk) {
      bf16x8 av0 = *(const bf16x8*)(Ps[wave][0] + (lr*8 + ((kk*4 + lk) ^ (lr >> 1)))*8);
      bf16x8 av1 = *(const bf16x8*)(Ps[wave][1] + (lr*8 + ((kk*4 + lk) ^ (lr >> 1)))*8);
      #pragma unroll
      for (int n = 0; n < 4; ++n) {
        int r = n*16 + lr;
        bf16x8 bv = *(const bf16x8*)(Vs[CUR] + (r*8 + ((kk*4 + lk) ^ (r & 7)))*8);
        oacc[0][n] = __builtin_amdgcn_mfma_f32_16x16x32_bf16(av0, bv, oacc[0][n], 0, 0, 0);
        oacc[1][n] = __builtin_amdgcn_mfma_f32_16x16x32_bf16(av1, bv, oacc[1][n], 0, 0, 0);
      }
    }
    __syncthreads();   // protects buf[CUR] restage at t+2; drains this tile's prefetch
  };

  for (int t = 0; t < NT; t += 2) {
    tile(IC<0>{}, t);
    tile(IC<1>{}, t + 1);
  }

  const float hm = head_mask[h];
  const int b = bh >> 4;
  #pragma unroll
  for (int mg = 0; mg < 2; ++mg)
    #pragma unroll
    for (int j = 0; j < 4; ++j) {
      int q = q0 + wave*32 + mg*16 + lk*4 + j;
      float inv = hm / row_l[mg][j];
      int rowbase = (b*SEQ + q)*HID + h*64;
      #pragma unroll
      for (int n = 0; n < 4; ++n)
        O[rowbase + n*16 + lr] = f2bf(oacc[mg][n][j] * inv);
    }
}

extern "C" void kernel_launch(void* const* d_in, const int* in_sizes, int n_in,
                              void* d_out, int out_size, void* d_ws, size_t ws_size,
                              hipStream_t stream) {
  const float* x  = (const float*)d_in[0];
  const float* Wq = (const float*)d_in[1];
  const float* bq = (const float*)d_in[2];
  const float* Wk = (const float*)d_in[3];
  const float* bk = (const float*)d_in[4];
  const float* Wv = (const float*)d_in[5];
  const float* bv = (const float*)d_in[6];
  const float* Wo = (const float*)d_in[7];
  const float* bo = (const float*)d_in[8];
  const float* hm = (const float*)d_in[9];
  float* out = (float*)d_out;
  char* ws = (char*)d_ws;

  short* xb  = (short*)(ws);
  short* wqb = (short*)(ws + 16777216);
  short* wkb = (short*)(ws + 18874368);
  short* wvb = (short*)(ws + 20971520);
  short* wob = (short*)(ws + 23068672);
  short* Qb  = (short*)(ws + 25165824);
  short* Kb  = (short*)(ws + 41943040);
  short* Vb  = (short*)(ws + 58720256);   // V^T [B,H,64,S]
  short* AOb = (short*)(ws + 75497472);

  cvt_f32_bf16<<<8192, 256, 0, stream>>>((const float4*)x,  (short4*)xb,  2097152);
  cvt_f32_bf16<<<1024, 256, 0, stream>>>((const float4*)Wq, (short4*)wqb, 262144);
  cvt_f32_bf16<<<1024, 256, 0, stream>>>((const float4*)Wk, (short4*)wkb, 262144);
  cvt_f32_bf16<<<1024, 256, 0, stream>>>((const float4*)Wv, (short4*)wvb, 262144);
  cvt_f32_bf16<<<1024, 256, 0, stream>>>((const float4*)Wo, (short4*)wob, 262144);

  gemm_bf16<0><<<dim3(24, 64), 256, 0, stream>>>(xb, wqb, wkb, wvb, bq, bk, bv,
                                                 Qb, Kb, Vb, nullptr);
  attn_fwd<<<dim3(SEQ/QBLK, 64), 256, 0, stream>>>(Qb, Kb, Vb, hm, AOb);
  gemm_bf16<1><<<dim3(8, 64), 256, 0, stream>>>(AOb, wob, nullptr, nullptr, bo, nullptr, nullptr,
                                                nullptr, nullptr, nullptr, out);
}

// Round 12
// 317.611 us; speedup vs baseline: 1.3107x; 1.2309x over previous
//
#include <hip/hip_runtime.h>
#include <hip/hip_bf16.h>

typedef __attribute__((ext_vector_type(8))) short bf16x8;
typedef __attribute__((ext_vector_type(4))) float f32x4;
typedef __attribute__((ext_vector_type(16))) float f32x16;
typedef unsigned int u32;

#define SEQ 2048
#define NB 4
#define NH 16
#define HID 1024
#define QBLK 128

__device__ __forceinline__ short f2bf(float f) {
  __hip_bfloat16 h = __float2bfloat16(f);
  union { __hip_bfloat16 h; short s; } u; u.h = h; return u.s;
}

__device__ __forceinline__ u32 pk2(float a, float b) {
  return (u32)(unsigned short)f2bf(a) | ((u32)(unsigned short)f2bf(b) << 16);
}

__device__ __forceinline__ void gload_lds16(const void* g, void* l) {
  __builtin_amdgcn_global_load_lds((const __attribute__((address_space(1))) void*)g,
                                   (__attribute__((address_space(3))) void*)l, 16, 0, 0);
}

__global__ void cvt_f32_bf16(const float4* __restrict__ in, short4* __restrict__ out, int n4) {
  int i = blockIdx.x * 256 + threadIdx.x;
  if (i >= n4) return;
  float4 v = in[i];
  short4 o;
  o.x = f2bf(v.x); o.y = f2bf(v.y); o.z = f2bf(v.z); o.w = f2bf(v.w);
  out[i] = o;
}

// C = A @ B^T (+bias). MODE 0: fused QKV -> Q,K [B,H,S,64] (Q*0.125), V^T [B,H,64,S].
// MODE 1: O-proj -> fp32 [M,1024] + bias.
template<int MODE>
__global__ __launch_bounds__(256, 2)
void gemm_bf16(const short* __restrict__ A,
               const short* __restrict__ B0, const short* __restrict__ B1, const short* __restrict__ B2,
               const float* __restrict__ bias0, const float* __restrict__ bias1, const float* __restrict__ bias2,
               short* __restrict__ o0, short* __restrict__ o1, short* __restrict__ o2,
               float* __restrict__ of) {
  __shared__ __align__(16) short As[128*64];
  __shared__ __align__(16) short Bs[128*64];
  const int tid = threadIdx.x;
  const int wave = tid >> 6, lane = tid & 63;
  const int lr = lane & 15, lk = lane >> 4;
  const int m0 = blockIdx.y * 128;
  const int n0 = blockIdx.x * 128;

  const short* Bm; const float* bias; int nloc; int proj = 0;
  if (MODE == 0) {
    proj = n0 >> 10;
    Bm   = proj == 0 ? B0 : (proj == 1 ? B1 : B2);
    bias = proj == 0 ? bias0 : (proj == 1 ? bias1 : bias2);
    nloc = n0 & 1023;
  } else { Bm = B0; bias = bias0; nloc = n0; }

  f32x4 acc[4][4];
  #pragma unroll
  for (int m = 0; m < 4; ++m)
    #pragma unroll
    for (int n = 0; n < 4; ++n) acc[m][n] = (f32x4){0.f,0.f,0.f,0.f};

  const int wr = (wave >> 1) * 64, wc = (wave & 1) * 64;

  for (int kt = 0; kt < 1024; kt += 64) {
    #pragma unroll
    for (int is = 0; is < 4; ++is) {
      int slot = is*256 + tid;
      int r = slot >> 3;
      int cs = (slot & 7) ^ (r & 7);
      gload_lds16(A  + (m0  + r)*1024 + kt + cs*8, As + (is*256 + wave*64)*8);
      gload_lds16(Bm + (nloc+ r)*1024 + kt + cs*8, Bs + (is*256 + wave*64)*8);
    }
    __syncthreads();
    #pragma unroll
    for (int kk = 0; kk < 2; ++kk) {
      bf16x8 av[4], bv[4];
      #pragma unroll
      for (int m = 0; m < 4; ++m) {
        int r = wr + m*16 + lr;
        av[m] = *(const bf16x8*)(As + (r*8 + ((kk*4 + lk) ^ (r & 7)))*8);
      }
      #pragma unroll
      for (int n = 0; n < 4; ++n) {
        int r = wc + n*16 + lr;
        bv[n] = *(const bf16x8*)(Bs + (r*8 + ((kk*4 + lk) ^ (r & 7)))*8);
      }
      #pragma unroll
      for (int m = 0; m < 4; ++m)
        #pragma unroll
        for (int n = 0; n < 4; ++n)
          acc[m][n] = __builtin_amdgcn_mfma_f32_16x16x32_bf16(av[m], bv[n], acc[m][n], 0, 0, 0);
    }
    __syncthreads();
  }

  if (MODE == 0) {
    if (proj < 2) {
      short* outp = proj == 0 ? o0 : o1;
      const float scale = (proj == 0) ? 0.125f : 1.0f;
      #pragma unroll
      for (int n = 0; n < 4; ++n) {
        int col = nloc + wc + n*16 + lr;
        int h = col >> 6, d = col & 63;
        float bvv = bias[col];
        #pragma unroll
        for (int m = 0; m < 4; ++m)
          #pragma unroll
          for (int j = 0; j < 4; ++j) {
            int row = m0 + wr + m*16 + lk*4 + j;
            int b = row >> 11, s = row & 2047;
            outp[(((b*NH + h)*SEQ + s) << 6) + d] = f2bf((acc[m][n][j] + bvv) * scale);
          }
      }
    } else {
      #pragma unroll
      for (int n = 0; n < 4; ++n) {
        int col = nloc + wc + n*16 + lr;
        int h = col >> 6, d = col & 63;
        float bvv = bias[col];
        #pragma unroll
        for (int m = 0; m < 4; ++m) {
          int row = m0 + wr + m*16 + lk*4;
          int b = row >> 11, s = row & 2047;
          short4 vv;
          vv.x = f2bf(acc[m][n][0] + bvv);
          vv.y = f2bf(acc[m][n][1] + bvv);
          vv.z = f2bf(acc[m][n][2] + bvv);
          vv.w = f2bf(acc[m][n][3] + bvv);
          *(short4*)(o2 + (((b*NH + h)*64 + d)*SEQ + s)) = vv;
        }
      }
    }
  } else {
    #pragma unroll
    for (int n = 0; n < 4; ++n) {
      int col = n0 + wc + n*16 + lr;
      float bvv = bias[col];
      #pragma unroll
      for (int m = 0; m < 4; ++m)
        #pragma unroll
        for (int j = 0; j < 4; ++j) {
          int row = m0 + wr + m*16 + lk*4 + j;
          of[row*HID + col] = acc[m][n][j] + bvv;
        }
    }
  }
}

// ---- attention helpers: plain template device functions (no lambdas) ----

template<int BUF>
__device__ __forceinline__ void attn_stage(int tid, int wave,
                                           const short* __restrict__ Kh,
                                           const short* __restrict__ Vh, int kv0,
                                           short (&Ks)[2][64*64], short (&Vs)[2][64*64]) {
  #pragma unroll
  for (int is = 0; is < 2; ++is) {
    int slot = is*256 + tid;
    int r = slot >> 3;
    int cs = (slot & 7) ^ (r & 7);
    gload_lds16(Kh + (kv0 + r)*64 + cs*8, Ks[BUF] + (is*256 + wave*64)*8);
    gload_lds16(Vh + r*SEQ + kv0 + cs*8, Vs[BUF] + (is*256 + wave*64)*8);
  }
}

template<int CUR>
__device__ __forceinline__ void attn_tile(int t, int NT, int tid, int wave, int qq, int hi,
                                          const short* __restrict__ Kh,
                                          const short* __restrict__ Vh,
                                          short (&Ks)[2][64*64], short (&Vs)[2][64*64],
                                          bf16x8 (&qf)[4], float& row_m, float& row_l,
                                          f32x16 (&oacc)[2]) {
  if (t + 1 < NT) attn_stage<CUR ^ 1>(tid, wave, Kh, Vh, (t + 1) * 64, Ks, Vs);

  // S^T[kv][q] = K · Q^T ; sc[kb] covers kv in [kb*32, +32)
  // lane holds: q = qq, kv = kb*32 + (reg&3) + 8*(reg>>2) + 4*hi
  f32x16 sc[2];
  #pragma unroll
  for (int i = 0; i < 16; ++i) { sc[0][i] = 0.f; sc[1][i] = 0.f; }
  #pragma unroll
  for (int kb = 0; kb < 2; ++kb) {
    int r = kb*32 + qq;
    #pragma unroll
    for (int ks = 0; ks < 4; ++ks) {
      bf16x8 ka = *(const bf16x8*)(Ks[CUR] + (r*8 + ((ks*2 + hi) ^ (r & 7)))*8);
      sc[kb] = __builtin_amdgcn_mfma_f32_32x32x16_bf16(ka, qf[ks], sc[kb], 0, 0, 0);
    }
  }

  // ---- softmax (per lane = one q-row; halves combined via lane^32) ----
  float tm[16];
  #pragma unroll
  for (int i = 0; i < 16; ++i) tm[i] = fmaxf(sc[0][i], sc[1][i]);
  #pragma unroll
  for (int s = 8; s >= 1; s >>= 1)
    #pragma unroll
    for (int i = 0; i < s; ++i) tm[i] = fmaxf(tm[i], tm[i + s]);
  float mt = fmaxf(tm[0], __shfl_xor(tm[0], 32));

  if (__any(mt > row_m + 8.f)) {    // defer-max (T13)
    float mn = fmaxf(row_m, mt);
    float ps = __expf(row_m - mn);
    row_m = mn;
    row_l *= ps;
    #pragma unroll
    for (int rg = 0; rg < 16; ++rg) {
      int qsrc = (rg & 3) + 8*(rg >> 2) + 4*hi;
      float po = __shfl(ps, qsrc);   // ps for the q-row held by oacc reg rg
      oacc[0][rg] *= po;
      oacc[1][rg] *= po;
    }
  }

  #pragma unroll
  for (int kb = 0; kb < 2; ++kb)
    #pragma unroll
    for (int i = 0; i < 16; ++i) sc[kb][i] = __expf(sc[kb][i] - row_m);

  // ---- P -> PV A-frags (q=lane&31, k=kv=ks*16+hi*8+j), in-register ----
  bf16x8 pa[4];
  #pragma unroll
  for (int ks = 0; ks < 4; ++ks) {
    int kvb = ks >> 1;
    int qe4 = (ks & 1) * 8;
    u32 we0 = pk2(sc[kvb][qe4+0], sc[kvb][qe4+1]);
    u32 we1 = pk2(sc[kvb][qe4+2], sc[kvb][qe4+3]);
    u32 wo0 = pk2(sc[kvb][qe4+4], sc[kvb][qe4+5]);
    u32 wo1 = pk2(sc[kvb][qe4+6], sc[kvb][qe4+7]);
    u32 s0 = hi ? we0 : wo0;         // send what partner needs
    u32 s1 = hi ? we1 : wo1;
    u32 r0 = (u32)__shfl_xor((int)s0, 32);
    u32 r1 = (u32)__shfl_xor((int)s1, 32);
    u32 k0 = hi ? wo0 : we0;         // keep own half
    u32 k1 = hi ? wo1 : we1;
    union { u32 u[4]; bf16x8 v; } pu;
    pu.u[0] = hi ? r0 : k0;
    pu.u[1] = hi ? r1 : k1;
    pu.u[2] = hi ? k0 : r0;
    pu.u[3] = hi ? k1 : r1;
    pa[ks] = pu.v;
  }

  // ---- O += P @ V : oacc[db] covers d in [db*32, +32) ----
  #pragma unroll
  for (int db = 0; db < 2; ++db) {
    int r = db*32 + qq;
    #pragma unroll
    for (int ks = 0; ks < 4; ++ks) {
      bf16x8 vb = *(const bf16x8*)(Vs[CUR] + (r*8 + ((ks*2 + hi) ^ (r & 7)))*8);
      oacc[db] = __builtin_amdgcn_mfma_f32_32x32x16_bf16(pa[ks], vb, oacc[db], 0, 0, 0);
    }
  }

  // ---- row sum (off PV critical path) ----
  float ts[16];
  #pragma unroll
  for (int i = 0; i < 16; ++i) ts[i] = sc[0][i] + sc[1][i];
  #pragma unroll
  for (int s = 8; s >= 1; s >>= 1)
    #pragma unroll
    for (int i = 0; i < s; ++i) ts[i] += ts[i + s];
  row_l += ts[0] + __shfl_xor(ts[0], 32);

  __syncthreads();   // gates restage of CUR at t+2; drains this tile's prefetch
}

// Flash attention, swapped-QK^T 32x32 structure (m214 pattern):
//  - S^T = mfma_32x32x16(A=K, B=Q): lane owns q = lane&31; kv split with lane^32.
//  - softmax fully in-register: in-lane trees + one shfl_xor(32); no P LDS round-trip.
//  - P -> PV A-frags via pack + one shfl_xor(32) exchange per k-slice.
//  - K [kv][d] and V^T [d][kv] tiles staged swizzled, static-CUR dbuf, 1 barrier/tile.
// Q,K: [B,H,S,64] bf16 (Q*0.125). VT: [B,H,64,S]. O: [B,S,H*64] bf16.
__global__ __launch_bounds__(256, 3)
void attn_fwd(const short* __restrict__ Q, const short* __restrict__ K,
              const short* __restrict__ VT, const float* __restrict__ head_mask,
              short* __restrict__ O) {
  __shared__ __align__(16) short Ks[2][64*64];   // [kv][d], swizzled slot^=(r&7)
  __shared__ __align__(16) short Vs[2][64*64];   // [d][kv], swizzled slot^=(r&7)
  const int tid = threadIdx.x;
  const int wave = tid >> 6, lane = tid & 63;
  const int qq = lane & 31;          // this lane's q-row (within wave's 32)
  const int hi = lane >> 5;          // kv half selector; partner = lane^32
  const int bh = blockIdx.y;
  const int h = bh & (NH - 1);
  const int q0 = blockIdx.x * QBLK;
  const short* Qh = Q  + bh * SEQ * 64;
  const short* Kh = K  + bh * SEQ * 64;
  const short* Vh = VT + bh * 64 * SEQ;

  // Q B-operand frags: col=q=lane&31, k = hi*8 + j, per d-slice ks (d = ks*16 + k)
  bf16x8 qf[4];
  {
    const short* qr = Qh + (q0 + wave*32 + qq)*64 + hi*8;
    #pragma unroll
    for (int ks = 0; ks < 4; ++ks) qf[ks] = *(const bf16x8*)(qr + ks*16);
  }

  float row_m = -1e30f, row_l = 0.f;
  f32x16 oacc[2];
  #pragma unroll
  for (int i = 0; i < 16; ++i) { oacc[0][i] = 0.f; oacc[1][i] = 0.f; }

  attn_stage<0>(tid, wave, Kh, Vh, 0, Ks, Vs);
  __syncthreads();

  const int NT = SEQ / 64;
  for (int t = 0; t < NT; t += 2) {
    attn_tile<0>(t,     NT, tid, wave, qq, hi, Kh, Vh, Ks, Vs, qf, row_m, row_l, oacc);
    attn_tile<1>(t + 1, NT, tid, wave, qq, hi, Kh, Vh, Ks, Vs, qf, row_m, row_l, oacc);
  }

  // Epilogue: O[q][d], oacc reg rg holds q = (rg&3)+8*(rg>>2)+4*hi, d = db*32+qq
  const float hm = head_mask[h];
  const int b = bh >> 4;
  float inv = hm / row_l;
  #pragma unroll
  for (int rg = 0; rg < 16; ++rg) {
    int qsrc = (rg & 3) + 8*(rg >> 2) + 4*hi;
    float io = __shfl(inv, qsrc);
    int orow = (b*SEQ + q0 + wave*32 + qsrc)*HID + h*64;
    O[orow + qq]      = f2bf(oacc[0][rg] * io);
    O[orow + 32 + qq] = f2bf(oacc[1][rg] * io);
  }
}

extern "C" void kernel_launch(void* const* d_in, const int* in_sizes, int n_in,
                              void* d_out, int out_size, void* d_ws, size_t ws_size,
                              hipStream_t stream) {
  const float* x  = (const float*)d_in[0];
  const float* Wq = (const float*)d_in[1];
  const float* bq = (const float*)d_in[2];
  const float* Wk = (const float*)d_in[3];
  const float* bk = (const float*)d_in[4];
  const float* Wv = (const float*)d_in[5];
  const float* bv = (const float*)d_in[6];
  const float* Wo = (const float*)d_in[7];
  const float* bo = (const float*)d_in[8];
  const float* hm = (const float*)d_in[9];
  float* out = (float*)d_out;
  char* ws = (char*)d_ws;

  short* xb  = (short*)(ws);
  short* wqb = (short*)(ws + 16777216);
  short* wkb = (short*)(ws + 18874368);
  short* wvb = (short*)(ws + 20971520);
  short* wob = (short*)(ws + 23068672);
  short* Qb  = (short*)(ws + 25165824);
  short* Kb  = (short*)(ws + 41943040);
  short* Vb  = (short*)(ws + 58720256);   // V^T [B,H,64,S]
  short* AOb = (short*)(ws + 75497472);

  cvt_f32_bf16<<<8192, 256, 0, stream>>>((const float4*)x,  (short4*)xb,  2097152);
  cvt_f32_bf16<<<1024, 256, 0, stream>>>((const float4*)Wq, (short4*)wqb, 262144);
  cvt_f32_bf16<<<1024, 256, 0, stream>>>((const float4*)Wk, (short4*)wkb, 262144);
  cvt_f32_bf16<<<1024, 256, 0, stream>>>((const float4*)Wv, (short4*)wvb, 262144);
  cvt_f32_bf16<<<1024, 256, 0, stream>>>((const float4*)Wo, (short4*)wob, 262144);

  gemm_bf16<0><<<dim3(24, 64), 256, 0, stream>>>(xb, wqb, wkb, wvb, bq, bk, bv,
                                                 Qb, Kb, Vb, nullptr);
  attn_fwd<<<dim3(SEQ/QBLK, 64), 256, 0, stream>>>(Qb, Kb, Vb, hm, AOb);
  gemm_bf16<1><<<dim3(8, 64), 256, 0, stream>>>(AOb, wob, nullptr, nullptr, bo, nullptr, nullptr,
                                                nullptr, nullptr, nullptr, out);
}